// Round 1
// baseline (403.980 us; speedup 1.0000x reference)
//
#include <hip/hip_runtime.h>
#include <cstdint>

#define HW 65536

// workspace float offsets
#define OFF_RSUM 0               // [2][4][64]
#define OFF_RMAX 512             // [2][4][64]
#define OFF_P    1024            // [2][4][64][64] row-major P matrices
#define OFF_POOL 33792           // [2][4][2][HW]  (ch0=mean, ch1=max)
#define OFF_T1   1082368         // [2][4][HW]
#define OFF_Y    1606656         // [2][4][HW]
#define OFF_MX   2130944         // [8]
#define OFF_IZ   2130952         // [8]

// ---------------- kernel 1: per-(t,b,c) sum & max over HW ----------------
__global__ __launch_bounds__(512) void k_reduce(const float* __restrict__ f1,
                                                const float* __restrict__ f2,
                                                float* __restrict__ ws) {
  int s = blockIdx.x;                    // 0..511 : t*256 + b*64 + c
  int t = s >> 8;
  const float* base = (t ? f2 : f1) + ((size_t)(s & 255) << 16);
  const float4* p4 = (const float4*)base;
  int tid = threadIdx.x;
  float sum = 0.f, mx = -3.4e38f;
#pragma unroll 8
  for (int it = 0; it < 32; ++it) {
    float4 v = p4[tid + (it << 9)];
    sum += (v.x + v.y) + (v.z + v.w);
    mx = fmaxf(mx, fmaxf(fmaxf(v.x, v.y), fmaxf(v.z, v.w)));
  }
  for (int o = 32; o > 0; o >>= 1) {
    sum += __shfl_down(sum, o);
    mx = fmaxf(mx, __shfl_down(mx, o));
  }
  __shared__ float ls[8], lm[8];
  int wid = tid >> 6, lane = tid & 63;
  if (lane == 0) { ls[wid] = sum; lm[wid] = mx; }
  __syncthreads();
  if (tid == 0) {
    float S = ls[0], M = lm[0];
    for (int w = 1; w < 8; ++w) { S += ls[w]; M = fmaxf(M, lm[w]); }
    ws[OFF_RSUM + s] = S;
    ws[OFF_RMAX + s] = M;
  }
}

// ---------------- kernel 2: descriptor MLPs + softmax P matrices ----------------
__global__ __launch_bounds__(64) void k_mlp(
    const float* __restrict__ wsin, float* __restrict__ wsP,
    const float* __restrict__ w_avg1, const float* __restrict__ b_avg1,
    const float* __restrict__ w_max1, const float* __restrict__ b_max1,
    const float* __restrict__ w_avg11, const float* __restrict__ b_avg11,
    const float* __restrict__ w_max11, const float* __restrict__ b_max11,
    const float* __restrict__ w_avg2, const float* __restrict__ b_avg2,
    const float* __restrict__ w_max2, const float* __restrict__ b_max2,
    const float* __restrict__ w_avg22, const float* __restrict__ b_avg22,
    const float* __restrict__ w_max22, const float* __restrict__ b_max22) {
  int b = blockIdx.x, tid = threadIdx.x;
  __shared__ float avg1[64], mx1[64], avg2[64], mx2[64];
  __shared__ float ha1[32], hm1[32], ha2[32], hm2[32];
  __shared__ float a1[64], a2[64];
  avg1[tid] = wsin[OFF_RSUM + b * 64 + tid] * (1.f / 65536.f);
  mx1[tid]  = wsin[OFF_RMAX + b * 64 + tid];
  avg2[tid] = wsin[OFF_RSUM + 256 + b * 64 + tid] * (1.f / 65536.f);
  mx2[tid]  = wsin[OFF_RMAX + 256 + b * 64 + tid];
  __syncthreads();
  if (tid < 32) {
    float s1 = b_avg1[tid], s2 = b_max1[tid], s3 = b_avg2[tid], s4 = b_max2[tid];
    for (int c = 0; c < 64; ++c) {
      s1 += w_avg1[tid * 64 + c] * avg1[c];
      s2 += w_max1[tid * 64 + c] * mx1[c];
      s3 += w_avg2[tid * 64 + c] * avg2[c];
      s4 += w_max2[tid * 64 + c] * mx2[c];
    }
    ha1[tid] = fmaxf(s1, 0.f); hm1[tid] = fmaxf(s2, 0.f);
    ha2[tid] = fmaxf(s3, 0.f); hm2[tid] = fmaxf(s4, 0.f);
  }
  __syncthreads();
  {
    float s1 = b_avg11[tid] + b_max11[tid];
    float s2 = b_avg22[tid] + b_max22[tid];
    for (int k = 0; k < 32; ++k) {
      s1 += w_avg11[tid * 32 + k] * ha1[k] + w_max11[tid * 32 + k] * hm1[k];
      s2 += w_avg22[tid * 32 + k] * ha2[k] + w_max22[tid * 32 + k] * hm2[k];
    }
    a1[tid] = s1; a2[tid] = s2;
  }
  __syncthreads();
  {  // P1 row tid: softmax_j(a1[tid]*a2[j])
    float s = a1[tid], m = -3.4e38f;
    for (int j = 0; j < 64; ++j) m = fmaxf(m, s * a2[j]);
    float sum = 0.f;
    for (int j = 0; j < 64; ++j) sum += __expf(s * a2[j] - m);
    float inv = 1.f / sum;
    float* row = wsP + (b << 12) + (tid << 6);
    for (int j = 0; j < 64; ++j) row[j] = __expf(s * a2[j] - m) * inv;
  }
  {  // P2 row tid: softmax_j(a2[tid]*a1[j])
    float s = a2[tid], m = -3.4e38f;
    for (int j = 0; j < 64; ++j) m = fmaxf(m, s * a1[j]);
    float sum = 0.f;
    for (int j = 0; j < 64; ++j) sum += __expf(s * a1[j] - m);
    float inv = 1.f / sum;
    float* row = wsP + ((4 + b) << 12) + (tid << 6);
    for (int j = 0; j < 64; ++j) row[j] = __expf(s * a1[j] - m) * inv;
  }
}

// ---------------- kernel 3: at = P@f, channel mean/max per pixel ----------------
__global__ __launch_bounds__(256) void k_pool(const float* __restrict__ f1,
                                              const float* __restrict__ f2,
                                              const float* __restrict__ wsP,
                                              float* __restrict__ pool) {
  int bx = blockIdx.x;            // 2048 blocks
  int t = bx >> 10;
  int r = bx & 1023;
  int b = r >> 8;
  int n = ((r & 255) << 8) | threadIdx.x;
  const float* f = (t ? f2 : f1) + ((size_t)b << 22) + n;
  const float* P = wsP + ((size_t)((t << 2) | b) << 12);
  float fv[64];
#pragma unroll
  for (int j = 0; j < 64; ++j) fv[j] = f[(size_t)j << 16];
  float msum = 0.f, mmax = -3.4e38f;
  for (int i = 0; i < 64; ++i) {
    const float* Pr = P + (i << 6);   // uniform address -> scalar loads
    float d0 = 0.f, d1 = 0.f, d2 = 0.f, d3 = 0.f;
#pragma unroll
    for (int j = 0; j < 64; j += 4) {
      d0 = fmaf(Pr[j    ], fv[j    ], d0);
      d1 = fmaf(Pr[j + 1], fv[j + 1], d1);
      d2 = fmaf(Pr[j + 2], fv[j + 2], d2);
      d3 = fmaf(Pr[j + 3], fv[j + 3], d3);
    }
    float at = (d0 + d1) + (d2 + d3);
    msum += at;
    mmax = fmaxf(mmax, at);
  }
  float* op = pool + (((size_t)((t << 2) | b)) << 17) + n;
  op[0]  = msum * (1.f / 64.f);
  op[HW] = mmax;
}

// ---------------- kernel 4: conv1 (2->1 ch, 3x3 SAME) + relu ----------------
__global__ __launch_bounds__(256) void k_conv1(const float* __restrict__ pool,
                                               float* __restrict__ t1,
                                               const float* __restrict__ cw,
                                               const float* __restrict__ cb) {
  int idx = blockIdx.x * 256 + threadIdx.x;   // 524288
  int t = idx >> 18;
  int rb = (idx >> 16) & 3;
  int n = idx & 65535;
  int h = n >> 8, w = n & 255;
  const float* pin = pool + ((size_t)((t << 2) | rb) << 17);
  float s = cb[0];
#pragma unroll
  for (int ci = 0; ci < 2; ++ci)
#pragma unroll
    for (int kh = -1; kh <= 1; ++kh)
#pragma unroll
      for (int kw = -1; kw <= 1; ++kw) {
        int hh = h + kh, ww = w + kw;
        if (hh >= 0 && hh < 256 && ww >= 0 && ww < 256)
          s += pin[ci * HW + (hh << 8) + ww] * cw[ci * 9 + (kh + 1) * 3 + (kw + 1)];
      }
  t1[((size_t)((t << 2) | rb) << 16) + n] = fmaxf(s, 0.f);
}

// ---------------- kernel 5: conv2 (1->1 ch, 3x3 SAME) ----------------
__global__ __launch_bounds__(256) void k_conv2(const float* __restrict__ t1,
                                               float* __restrict__ y,
                                               const float* __restrict__ cw,
                                               const float* __restrict__ cb) {
  int idx = blockIdx.x * 256 + threadIdx.x;
  int t = idx >> 18;
  int rb = (idx >> 16) & 3;
  int n = idx & 65535;
  int h = n >> 8, w = n & 255;
  const float* pin = t1 + ((size_t)((t << 2) | rb) << 16);
  float s = cb[0];
#pragma unroll
  for (int kh = -1; kh <= 1; ++kh)
#pragma unroll
    for (int kw = -1; kw <= 1; ++kw) {
      int hh = h + kh, ww = w + kw;
      if (hh >= 0 && hh < 256 && ww >= 0 && ww < 256)
        s += pin[(hh << 8) + ww] * cw[(kh + 1) * 3 + (kw + 1)];
    }
  y[((size_t)((t << 2) | rb) << 16) + n] = s;
}

// ---------------- kernel 6: per-slice max of y ----------------
__global__ __launch_bounds__(1024) void k_max(const float* __restrict__ y,
                                              float* __restrict__ mx) {
  int s = blockIdx.x;   // 0..7
  const float4* p = (const float4*)(y + ((size_t)s << 16));
  int tid = threadIdx.x;
  float m = -3.4e38f;
#pragma unroll
  for (int it = 0; it < 16; ++it) {
    float4 v = p[tid + (it << 10)];
    m = fmaxf(m, fmaxf(fmaxf(v.x, v.y), fmaxf(v.z, v.w)));
  }
  for (int o = 32; o > 0; o >>= 1) m = fmaxf(m, __shfl_down(m, o));
  __shared__ float lm[16];
  if ((tid & 63) == 0) lm[tid >> 6] = m;
  __syncthreads();
  if (tid == 0) {
    float M = lm[0];
    for (int w = 1; w < 16; ++w) M = fmaxf(M, lm[w]);
    mx[s] = M;
  }
}

// ---------------- kernel 7: per-slice sum(exp(y-mx)) -> 1/Z ----------------
__global__ __launch_bounds__(1024) void k_sumexp(const float* __restrict__ y,
                                                 const float* __restrict__ mx,
                                                 float* __restrict__ iz) {
  int s = blockIdx.x;
  float M = mx[s];
  const float4* p = (const float4*)(y + ((size_t)s << 16));
  int tid = threadIdx.x;
  float sum = 0.f;
#pragma unroll
  for (int it = 0; it < 16; ++it) {
    float4 v = p[tid + (it << 10)];
    sum += (__expf(v.x - M) + __expf(v.y - M)) + (__expf(v.z - M) + __expf(v.w - M));
  }
  for (int o = 32; o > 0; o >>= 1) sum += __shfl_down(sum, o);
  __shared__ float ls[16];
  if ((tid & 63) == 0) ls[tid >> 6] = sum;
  __syncthreads();
  if (tid == 0) {
    float S = ls[0];
    for (int w = 1; w < 16; ++w) S += ls[w];
    iz[s] = 1.f / S;
  }
}

// ---------------- kernel 8: o = f * (1 + g) ----------------
__global__ __launch_bounds__(256) void k_final(const float* __restrict__ f1,
                                               const float* __restrict__ f2,
                                               const float* __restrict__ y,
                                               const float* __restrict__ mx,
                                               const float* __restrict__ iz,
                                               float* __restrict__ out) {
  size_t idx = (size_t)blockIdx.x * 256 + threadIdx.x;  // float4 index
  size_t e = idx << 2;
  int t = (int)(e >> 24);
  int r = (int)(e & 16777215);
  int b = r >> 22;
  int n = r & 65535;
  int s = (t << 2) | b;
  float M = mx[s], Z = iz[s];
  float4 yv = *(const float4*)(y + ((size_t)s << 16) + n);
  float4 fv = *(const float4*)((t ? f2 : f1) + r);
  float4 o;
  o.x = fv.x * (1.f + __expf(yv.x - M) * Z);
  o.y = fv.y * (1.f + __expf(yv.y - M) * Z);
  o.z = fv.z * (1.f + __expf(yv.z - M) * Z);
  o.w = fv.w * (1.f + __expf(yv.w - M) * Z);
  *(float4*)(out + e) = o;
}

extern "C" void kernel_launch(void* const* d_in, const int* in_sizes, int n_in,
                              void* d_out, int out_size, void* d_ws, size_t ws_size,
                              hipStream_t stream) {
  const float* f1 = (const float*)d_in[0];
  const float* f2 = (const float*)d_in[1];
  const float* w_avg1  = (const float*)d_in[2];
  const float* b_avg1  = (const float*)d_in[3];
  const float* w_max1  = (const float*)d_in[4];
  const float* b_max1  = (const float*)d_in[5];
  const float* w_avg11 = (const float*)d_in[6];
  const float* b_avg11 = (const float*)d_in[7];
  const float* w_max11 = (const float*)d_in[8];
  const float* b_max11 = (const float*)d_in[9];
  const float* w_avg2  = (const float*)d_in[10];
  const float* b_avg2  = (const float*)d_in[11];
  const float* w_max2  = (const float*)d_in[12];
  const float* b_max2  = (const float*)d_in[13];
  const float* w_avg22 = (const float*)d_in[14];
  const float* b_avg22 = (const float*)d_in[15];
  const float* w_max22 = (const float*)d_in[16];
  const float* b_max22 = (const float*)d_in[17];
  const float* conv1_w = (const float*)d_in[18];
  const float* conv1_b = (const float*)d_in[19];
  const float* conv2_w = (const float*)d_in[20];
  const float* conv2_b = (const float*)d_in[21];
  float* ws = (float*)d_ws;
  float* out = (float*)d_out;

  k_reduce<<<512, 512, 0, stream>>>(f1, f2, ws);
  k_mlp<<<4, 64, 0, stream>>>(ws, ws + OFF_P,
                              w_avg1, b_avg1, w_max1, b_max1,
                              w_avg11, b_avg11, w_max11, b_max11,
                              w_avg2, b_avg2, w_max2, b_max2,
                              w_avg22, b_avg22, w_max22, b_max22);
  k_pool<<<2048, 256, 0, stream>>>(f1, f2, ws + OFF_P, ws + OFF_POOL);
  k_conv1<<<2048, 256, 0, stream>>>(ws + OFF_POOL, ws + OFF_T1, conv1_w, conv1_b);
  k_conv2<<<2048, 256, 0, stream>>>(ws + OFF_T1, ws + OFF_Y, conv2_w, conv2_b);
  k_max<<<8, 1024, 0, stream>>>(ws + OFF_Y, ws + OFF_MX);
  k_sumexp<<<8, 1024, 0, stream>>>(ws + OFF_Y, ws + OFF_MX, ws + OFF_IZ);
  k_final<<<32768, 256, 0, stream>>>(f1, f2, ws + OFF_Y, ws + OFF_MX, ws + OFF_IZ, out);
}

// Round 2
// 389.530 us; speedup vs baseline: 1.0371x; 1.0371x over previous
//
#include <hip/hip_runtime.h>
#include <hip/hip_fp16.h>
#include <cstdint>

#define HW 65536

// workspace float offsets
#define OFF_RSUM 0               // [2][4][64]
#define OFF_RMAX 512             // [2][4][64]
#define OFF_PH   1024            // [2][4][64][64] half2-duplicated P (1 dword each)
#define OFF_POOL 33792           // [2][4][2][HW]  (ch0=mean, ch1=max)
#define OFF_T1   1082368         // [2][4][HW]
#define OFF_Y    1606656         // [2][4][HW]
#define OFF_MX   2130944         // [8]
#define OFF_IZ   2130952         // [8]

// ---------------- kernel 1: per-(t,b,c) sum & max over HW ----------------
__global__ __launch_bounds__(512) void k_reduce(const float* __restrict__ f1,
                                                const float* __restrict__ f2,
                                                float* __restrict__ ws) {
  int s = blockIdx.x;                    // 0..511 : t*256 + b*64 + c
  int t = s >> 8;
  const float* base = (t ? f2 : f1) + ((size_t)(s & 255) << 16);
  const float4* p4 = (const float4*)base;
  int tid = threadIdx.x;
  float sum = 0.f, mx = -3.4e38f;
#pragma unroll 8
  for (int it = 0; it < 32; ++it) {
    float4 v = p4[tid + (it << 9)];
    sum += (v.x + v.y) + (v.z + v.w);
    mx = fmaxf(mx, fmaxf(fmaxf(v.x, v.y), fmaxf(v.z, v.w)));
  }
  for (int o = 32; o > 0; o >>= 1) {
    sum += __shfl_down(sum, o);
    mx = fmaxf(mx, __shfl_down(mx, o));
  }
  __shared__ float ls[8], lm[8];
  int wid = tid >> 6, lane = tid & 63;
  if (lane == 0) { ls[wid] = sum; lm[wid] = mx; }
  __syncthreads();
  if (tid == 0) {
    float S = ls[0], M = lm[0];
    for (int w = 1; w < 8; ++w) { S += ls[w]; M = fmaxf(M, lm[w]); }
    ws[OFF_RSUM + s] = S;
    ws[OFF_RMAX + s] = M;
  }
}

// ---------------- kernel 2: descriptor MLPs + softmax P (as dup-half2) ----------------
__global__ __launch_bounds__(64) void k_mlp(
    const float* __restrict__ wsin, unsigned int* __restrict__ wsPH,
    const float* __restrict__ w_avg1, const float* __restrict__ b_avg1,
    const float* __restrict__ w_max1, const float* __restrict__ b_max1,
    const float* __restrict__ w_avg11, const float* __restrict__ b_avg11,
    const float* __restrict__ w_max11, const float* __restrict__ b_max11,
    const float* __restrict__ w_avg2, const float* __restrict__ b_avg2,
    const float* __restrict__ w_max2, const float* __restrict__ b_max2,
    const float* __restrict__ w_avg22, const float* __restrict__ b_avg22,
    const float* __restrict__ w_max22, const float* __restrict__ b_max22) {
  int b = blockIdx.x, tid = threadIdx.x;
  __shared__ float avg1[64], mx1[64], avg2[64], mx2[64];
  __shared__ float ha1[32], hm1[32], ha2[32], hm2[32];
  __shared__ float a1[64], a2[64];
  avg1[tid] = wsin[OFF_RSUM + b * 64 + tid] * (1.f / 65536.f);
  mx1[tid]  = wsin[OFF_RMAX + b * 64 + tid];
  avg2[tid] = wsin[OFF_RSUM + 256 + b * 64 + tid] * (1.f / 65536.f);
  mx2[tid]  = wsin[OFF_RMAX + 256 + b * 64 + tid];
  __syncthreads();
  if (tid < 32) {
    float s1 = b_avg1[tid], s2 = b_max1[tid], s3 = b_avg2[tid], s4 = b_max2[tid];
    for (int c = 0; c < 64; ++c) {
      s1 += w_avg1[tid * 64 + c] * avg1[c];
      s2 += w_max1[tid * 64 + c] * mx1[c];
      s3 += w_avg2[tid * 64 + c] * avg2[c];
      s4 += w_max2[tid * 64 + c] * mx2[c];
    }
    ha1[tid] = fmaxf(s1, 0.f); hm1[tid] = fmaxf(s2, 0.f);
    ha2[tid] = fmaxf(s3, 0.f); hm2[tid] = fmaxf(s4, 0.f);
  }
  __syncthreads();
  {
    float s1 = b_avg11[tid] + b_max11[tid];
    float s2 = b_avg22[tid] + b_max22[tid];
    for (int k = 0; k < 32; ++k) {
      s1 += w_avg11[tid * 32 + k] * ha1[k] + w_max11[tid * 32 + k] * hm1[k];
      s2 += w_avg22[tid * 32 + k] * ha2[k] + w_max22[tid * 32 + k] * hm2[k];
    }
    a1[tid] = s1; a2[tid] = s2;
  }
  __syncthreads();
  {  // P1 row tid: softmax_j(a1[tid]*a2[j]) -> duplicated half2
    float s = a1[tid], m = -3.4e38f;
    for (int j = 0; j < 64; ++j) m = fmaxf(m, s * a2[j]);
    float sum = 0.f;
    for (int j = 0; j < 64; ++j) sum += __expf(s * a2[j] - m);
    float inv = 1.f / sum;
    __half2* row = (__half2*)(wsPH + (b << 12) + (tid << 6));
    for (int j = 0; j < 64; ++j) {
      __half p = __float2half_rn(__expf(s * a2[j] - m) * inv);
      row[j] = __halves2half2(p, p);
    }
  }
  {  // P2 row tid: softmax_j(a2[tid]*a1[j])
    float s = a2[tid], m = -3.4e38f;
    for (int j = 0; j < 64; ++j) m = fmaxf(m, s * a1[j]);
    float sum = 0.f;
    for (int j = 0; j < 64; ++j) sum += __expf(s * a1[j] - m);
    float inv = 1.f / sum;
    __half2* row = (__half2*)(wsPH + ((4 + b) << 12) + (tid << 6));
    for (int j = 0; j < 64; ++j) {
      __half p = __float2half_rn(__expf(s * a1[j] - m) * inv);
      row[j] = __halves2half2(p, p);
    }
  }
}

// ---------------- kernel 3: at = P@f via pk-f16, channel mean/max, 2 px/thread ----------------
__global__ __launch_bounds__(256) void k_pool(const float* __restrict__ f1,
                                              const float* __restrict__ f2,
                                              const unsigned int* __restrict__ wsPH,
                                              float* __restrict__ pool) {
  int bx = blockIdx.x;            // 1024 blocks, 512 pixels each
  int t = bx >> 9;
  int b = (bx >> 7) & 3;
  int n2 = ((bx & 127) << 9) | (threadIdx.x << 1);   // first pixel of the pair
  const float* f = (t ? f2 : f1) + ((size_t)b << 22);
  const __half2* P = (const __half2*)wsPH + ((size_t)((t << 2) | b) << 12);
  const float2* fp = (const float2*)f;
  __half2 fv[64];
#pragma unroll
  for (int j = 0; j < 64; ++j) {
    float2 v = fp[(j << 15) + (n2 >> 1)];
    fv[j] = __floats2half2_rn(v.x, v.y);
  }
  float sx = 0.f, sy = 0.f, mxx = -3.4e38f, mxy = -3.4e38f;
#pragma unroll 2
  for (int i = 0; i < 64; ++i) {
    const __half2* Pr = P + (i << 6);   // wave-uniform -> scalar loads
    __half2 a0 = __float2half2_rn(0.f), a1 = a0, a2 = a0, a3 = a0;
#pragma unroll
    for (int j = 0; j < 64; j += 4) {
      a0 = __hfma2(Pr[j    ], fv[j    ], a0);
      a1 = __hfma2(Pr[j + 1], fv[j + 1], a1);
      a2 = __hfma2(Pr[j + 2], fv[j + 2], a2);
      a3 = __hfma2(Pr[j + 3], fv[j + 3], a3);
    }
    __half2 at = __hadd2(__hadd2(a0, a1), __hadd2(a2, a3));
    float2 atf = __half22float2(at);
    sx += atf.x; sy += atf.y;
    mxx = fmaxf(mxx, atf.x); mxy = fmaxf(mxy, atf.y);
  }
  float* op = pool + (((size_t)((t << 2) | b)) << 17) + n2;
  op[0] = sx * (1.f / 64.f);
  op[1] = sy * (1.f / 64.f);
  op[HW] = mxx;
  op[HW + 1] = mxy;
}

// ---------------- kernel 4: conv1 (2->1 ch, 3x3 SAME) + relu ----------------
__global__ __launch_bounds__(256) void k_conv1(const float* __restrict__ pool,
                                               float* __restrict__ t1,
                                               const float* __restrict__ cw,
                                               const float* __restrict__ cb) {
  int idx = blockIdx.x * 256 + threadIdx.x;   // 524288
  int t = idx >> 18;
  int rb = (idx >> 16) & 3;
  int n = idx & 65535;
  int h = n >> 8, w = n & 255;
  const float* pin = pool + ((size_t)((t << 2) | rb) << 17);
  float s = cb[0];
#pragma unroll
  for (int ci = 0; ci < 2; ++ci)
#pragma unroll
    for (int kh = -1; kh <= 1; ++kh)
#pragma unroll
      for (int kw = -1; kw <= 1; ++kw) {
        int hh = h + kh, ww = w + kw;
        if (hh >= 0 && hh < 256 && ww >= 0 && ww < 256)
          s += pin[ci * HW + (hh << 8) + ww] * cw[ci * 9 + (kh + 1) * 3 + (kw + 1)];
      }
  t1[((size_t)((t << 2) | rb) << 16) + n] = fmaxf(s, 0.f);
}

// ---------------- kernel 5: conv2 (1->1 ch, 3x3 SAME) ----------------
__global__ __launch_bounds__(256) void k_conv2(const float* __restrict__ t1,
                                               float* __restrict__ y,
                                               const float* __restrict__ cw,
                                               const float* __restrict__ cb) {
  int idx = blockIdx.x * 256 + threadIdx.x;
  int t = idx >> 18;
  int rb = (idx >> 16) & 3;
  int n = idx & 65535;
  int h = n >> 8, w = n & 255;
  const float* pin = t1 + ((size_t)((t << 2) | rb) << 16);
  float s = cb[0];
#pragma unroll
  for (int kh = -1; kh <= 1; ++kh)
#pragma unroll
    for (int kw = -1; kw <= 1; ++kw) {
      int hh = h + kh, ww = w + kw;
      if (hh >= 0 && hh < 256 && ww >= 0 && ww < 256)
        s += pin[(hh << 8) + ww] * cw[(kh + 1) * 3 + (kw + 1)];
    }
  y[((size_t)((t << 2) | rb) << 16) + n] = s;
}

// ---------------- kernel 6: fused per-slice max + sum(exp) ----------------
__global__ __launch_bounds__(1024) void k_softstats(const float* __restrict__ y,
                                                    float* __restrict__ mx,
                                                    float* __restrict__ iz) {
  int s = blockIdx.x;   // 0..7
  const float4* p = (const float4*)(y + ((size_t)s << 16));
  int tid = threadIdx.x;
  float m = -3.4e38f;
#pragma unroll
  for (int it = 0; it < 16; ++it) {
    float4 v = p[tid + (it << 10)];
    m = fmaxf(m, fmaxf(fmaxf(v.x, v.y), fmaxf(v.z, v.w)));
  }
  for (int o = 32; o > 0; o >>= 1) m = fmaxf(m, __shfl_down(m, o));
  __shared__ float lm[16];
  __shared__ float Msh;
  if ((tid & 63) == 0) lm[tid >> 6] = m;
  __syncthreads();
  if (tid == 0) {
    float M = lm[0];
    for (int w = 1; w < 16; ++w) M = fmaxf(M, lm[w]);
    Msh = M;
    mx[s] = M;
  }
  __syncthreads();
  float M = Msh;
  float sum = 0.f;
#pragma unroll
  for (int it = 0; it < 16; ++it) {
    float4 v = p[tid + (it << 10)];
    sum += (__expf(v.x - M) + __expf(v.y - M)) + (__expf(v.z - M) + __expf(v.w - M));
  }
  for (int o = 32; o > 0; o >>= 1) sum += __shfl_down(sum, o);
  __shared__ float ls[16];
  if ((tid & 63) == 0) ls[tid >> 6] = sum;
  __syncthreads();
  if (tid == 0) {
    float S = ls[0];
    for (int w = 1; w < 16; ++w) S += ls[w];
    iz[s] = 1.f / S;
  }
}

// ---------------- kernel 7: o = f * (1 + g) ----------------
__global__ __launch_bounds__(256) void k_final(const float* __restrict__ f1,
                                               const float* __restrict__ f2,
                                               const float* __restrict__ y,
                                               const float* __restrict__ mx,
                                               const float* __restrict__ iz,
                                               float* __restrict__ out) {
  size_t idx = (size_t)blockIdx.x * 256 + threadIdx.x;  // float4 index
  size_t e = idx << 2;
  int t = (int)(e >> 24);
  int r = (int)(e & 16777215);
  int b = r >> 22;
  int n = r & 65535;
  int s = (t << 2) | b;
  float M = mx[s], Z = iz[s];
  float4 yv = *(const float4*)(y + ((size_t)s << 16) + n);
  float4 fv = *(const float4*)((t ? f2 : f1) + r);
  float4 o;
  o.x = fv.x * (1.f + __expf(yv.x - M) * Z);
  o.y = fv.y * (1.f + __expf(yv.y - M) * Z);
  o.z = fv.z * (1.f + __expf(yv.z - M) * Z);
  o.w = fv.w * (1.f + __expf(yv.w - M) * Z);
  *(float4*)(out + e) = o;
}

extern "C" void kernel_launch(void* const* d_in, const int* in_sizes, int n_in,
                              void* d_out, int out_size, void* d_ws, size_t ws_size,
                              hipStream_t stream) {
  const float* f1 = (const float*)d_in[0];
  const float* f2 = (const float*)d_in[1];
  const float* w_avg1  = (const float*)d_in[2];
  const float* b_avg1  = (const float*)d_in[3];
  const float* w_max1  = (const float*)d_in[4];
  const float* b_max1  = (const float*)d_in[5];
  const float* w_avg11 = (const float*)d_in[6];
  const float* b_avg11 = (const float*)d_in[7];
  const float* w_max11 = (const float*)d_in[8];
  const float* b_max11 = (const float*)d_in[9];
  const float* w_avg2  = (const float*)d_in[10];
  const float* b_avg2  = (const float*)d_in[11];
  const float* w_max2  = (const float*)d_in[12];
  const float* b_max2  = (const float*)d_in[13];
  const float* w_avg22 = (const float*)d_in[14];
  const float* b_avg22 = (const float*)d_in[15];
  const float* w_max22 = (const float*)d_in[16];
  const float* b_max22 = (const float*)d_in[17];
  const float* conv1_w = (const float*)d_in[18];
  const float* conv1_b = (const float*)d_in[19];
  const float* conv2_w = (const float*)d_in[20];
  const float* conv2_b = (const float*)d_in[21];
  float* ws = (float*)d_ws;
  float* out = (float*)d_out;

  k_reduce<<<512, 512, 0, stream>>>(f1, f2, ws);
  k_mlp<<<4, 64, 0, stream>>>(ws, (unsigned int*)(ws + OFF_PH),
                              w_avg1, b_avg1, w_max1, b_max1,
                              w_avg11, b_avg11, w_max11, b_max11,
                              w_avg2, b_avg2, w_max2, b_max2,
                              w_avg22, b_avg22, w_max22, b_max22);
  k_pool<<<1024, 256, 0, stream>>>(f1, f2, (const unsigned int*)(ws + OFF_PH),
                                   ws + OFF_POOL);
  k_conv1<<<2048, 256, 0, stream>>>(ws + OFF_POOL, ws + OFF_T1, conv1_w, conv1_b);
  k_conv2<<<2048, 256, 0, stream>>>(ws + OFF_T1, ws + OFF_Y, conv2_w, conv2_b);
  k_softstats<<<8, 1024, 0, stream>>>(ws + OFF_Y, ws + OFF_MX, ws + OFF_IZ);
  k_final<<<32768, 256, 0, stream>>>(f1, f2, ws + OFF_Y, ws + OFF_MX, ws + OFF_IZ, out);
}

// Round 3
// 337.028 us; speedup vs baseline: 1.1987x; 1.1558x over previous
//
#include <hip/hip_runtime.h>
#include <hip/hip_bf16.h>
#include <cstdint>

#define HW 65536

typedef __attribute__((ext_vector_type(8))) short bf16x8;   // 8 bf16 = 4 VGPRs
typedef __attribute__((ext_vector_type(4))) float f32x4;

// workspace float offsets
#define OFF_RSUM 0               // [2][4][64]
#define OFF_RMAX 512             // [2][4][64]
#define OFF_PB   1024            // [2][4][64][64] bf16 row-major P (16384 floats)
#define OFF_POOL 33792           // [2][4][2][HW]  (ch0=mean, ch1=max)
#define OFF_BM   33792           // [2048] per-block y max   (reuses dead pool region)
#define OFF_BS   35840           // [2048] per-block sumexp  (reuses dead pool region)
#define OFF_T1   1082368         // [2][4][HW]
#define OFF_Y    1606656         // [2][4][HW]
#define OFF_MX   2130944         // [8]
#define OFF_IZ   2130952         // [8]

// ---------------- kernel 1: per-(t,b,c) sum & max over HW ----------------
__global__ __launch_bounds__(512) void k_reduce(const float* __restrict__ f1,
                                                const float* __restrict__ f2,
                                                float* __restrict__ ws) {
  int s = blockIdx.x;                    // 0..511 : t*256 + b*64 + c
  int t = s >> 8;
  const float* base = (t ? f2 : f1) + ((size_t)(s & 255) << 16);
  const float4* p4 = (const float4*)base;
  int tid = threadIdx.x;
  float sum = 0.f, mx = -3.4e38f;
#pragma unroll 8
  for (int it = 0; it < 32; ++it) {
    float4 v = p4[tid + (it << 9)];
    sum += (v.x + v.y) + (v.z + v.w);
    mx = fmaxf(mx, fmaxf(fmaxf(v.x, v.y), fmaxf(v.z, v.w)));
  }
  for (int o = 32; o > 0; o >>= 1) {
    sum += __shfl_down(sum, o);
    mx = fmaxf(mx, __shfl_down(mx, o));
  }
  __shared__ float ls[8], lm[8];
  int wid = tid >> 6, lane = tid & 63;
  if (lane == 0) { ls[wid] = sum; lm[wid] = mx; }
  __syncthreads();
  if (tid == 0) {
    float S = ls[0], M = lm[0];
    for (int w = 1; w < 8; ++w) { S += ls[w]; M = fmaxf(M, lm[w]); }
    ws[OFF_RSUM + s] = S;
    ws[OFF_RMAX + s] = M;
  }
}

// ---------------- kernel 2: descriptor MLPs + softmax P (bf16 row-major) ----------------
__global__ __launch_bounds__(64) void k_mlp(
    const float* __restrict__ wsin, __hip_bfloat16* __restrict__ Pb,
    const float* __restrict__ w_avg1, const float* __restrict__ b_avg1,
    const float* __restrict__ w_max1, const float* __restrict__ b_max1,
    const float* __restrict__ w_avg11, const float* __restrict__ b_avg11,
    const float* __restrict__ w_max11, const float* __restrict__ b_max11,
    const float* __restrict__ w_avg2, const float* __restrict__ b_avg2,
    const float* __restrict__ w_max2, const float* __restrict__ b_max2,
    const float* __restrict__ w_avg22, const float* __restrict__ b_avg22,
    const float* __restrict__ w_max22, const float* __restrict__ b_max22) {
  int b = blockIdx.x, tid = threadIdx.x;
  __shared__ float avg1[64], mx1[64], avg2[64], mx2[64];
  __shared__ float ha1[32], hm1[32], ha2[32], hm2[32];
  __shared__ float a1[64], a2[64];
  avg1[tid] = wsin[OFF_RSUM + b * 64 + tid] * (1.f / 65536.f);
  mx1[tid]  = wsin[OFF_RMAX + b * 64 + tid];
  avg2[tid] = wsin[OFF_RSUM + 256 + b * 64 + tid] * (1.f / 65536.f);
  mx2[tid]  = wsin[OFF_RMAX + 256 + b * 64 + tid];
  __syncthreads();
  if (tid < 32) {
    float s1 = b_avg1[tid], s2 = b_max1[tid], s3 = b_avg2[tid], s4 = b_max2[tid];
    for (int c = 0; c < 64; ++c) {
      s1 += w_avg1[tid * 64 + c] * avg1[c];
      s2 += w_max1[tid * 64 + c] * mx1[c];
      s3 += w_avg2[tid * 64 + c] * avg2[c];
      s4 += w_max2[tid * 64 + c] * mx2[c];
    }
    ha1[tid] = fmaxf(s1, 0.f); hm1[tid] = fmaxf(s2, 0.f);
    ha2[tid] = fmaxf(s3, 0.f); hm2[tid] = fmaxf(s4, 0.f);
  }
  __syncthreads();
  {
    float s1 = b_avg11[tid] + b_max11[tid];
    float s2 = b_avg22[tid] + b_max22[tid];
    for (int k = 0; k < 32; ++k) {
      s1 += w_avg11[tid * 32 + k] * ha1[k] + w_max11[tid * 32 + k] * hm1[k];
      s2 += w_avg22[tid * 32 + k] * ha2[k] + w_max22[tid * 32 + k] * hm2[k];
    }
    a1[tid] = s1; a2[tid] = s2;
  }
  __syncthreads();
  {  // P1 row tid: softmax_j(a1[tid]*a2[j])
    float s = a1[tid], m = -3.4e38f;
    for (int j = 0; j < 64; ++j) m = fmaxf(m, s * a2[j]);
    float sum = 0.f;
    for (int j = 0; j < 64; ++j) sum += __expf(s * a2[j] - m);
    float inv = 1.f / sum;
    __hip_bfloat16* row = Pb + (b << 12) + (tid << 6);
    for (int j = 0; j < 64; ++j)
      row[j] = __float2bfloat16(__expf(s * a2[j] - m) * inv);
  }
  {  // P2 row tid: softmax_j(a2[tid]*a1[j])
    float s = a2[tid], m = -3.4e38f;
    for (int j = 0; j < 64; ++j) m = fmaxf(m, s * a1[j]);
    float sum = 0.f;
    for (int j = 0; j < 64; ++j) sum += __expf(s * a1[j] - m);
    float inv = 1.f / sum;
    __hip_bfloat16* row = Pb + ((4 + b) << 12) + (tid << 6);
    for (int j = 0; j < 64; ++j)
      row[j] = __float2bfloat16(__expf(s * a1[j] - m) * inv);
  }
}

// ---------------- kernel 3: at = P@f via MFMA, channel mean/max per pixel ----------------
// A = P (64x64 bf16), B = f (64 x HW), D = at. Per wave: 64 pixels (4 N-tiles).
// Layouts (16x16x32 bf16): A[m=lane&15][k=q*8+j], B[k=q*8+j][n=lane&15],
// D: col=lane&15, row=q*4+reg.
__global__ __launch_bounds__(256) void k_pool(const float* __restrict__ f1,
                                              const float* __restrict__ f2,
                                              const __hip_bfloat16* __restrict__ Pall,
                                              float* __restrict__ pool) {
  int bx = blockIdx.x;                 // 2048: slice = bx>>8, chunk = bx&255
  int slice = bx >> 8;
  int t = slice >> 2;
  const float* f = (t ? f2 : f1) + ((size_t)(slice & 3) << 22);
  const __hip_bfloat16* P = Pall + (slice << 12);
  int wave = threadIdx.x >> 6, lane = threadIdx.x & 63;
  int c = lane & 15, q = lane >> 4;
  int n0 = ((bx & 255) << 8) + (wave << 6);   // this wave's 64-pixel base

  // A fragments: P rows mt*16+c, k = s*32 + q*8 .. +7 (16B each)
  bf16x8 A[4][2];
#pragma unroll
  for (int mt = 0; mt < 4; ++mt)
#pragma unroll
    for (int s = 0; s < 2; ++s)
      A[mt][s] = *(const bf16x8*)(P + ((mt * 16 + c) << 6) + s * 32 + q * 8);

  const float* fq = f + (size_t)(q * 8) * HW + n0 + c;   // lane's B base
  float* poolp = pool + ((size_t)slice << 17);

#pragma unroll 2
  for (int nt = 0; nt < 4; ++nt) {
    int d = nt << 4;
    float bv0[8], bv1[8];
#pragma unroll
    for (int j = 0; j < 8; ++j) {
      bv0[j] = fq[(size_t)j * HW + d];          // k = q*8+j        (s=0)
      bv1[j] = fq[(size_t)(j + 32) * HW + d];   // k = 32 + q*8+j   (s=1)
    }
    union { bf16x8 v; __hip_bfloat162 h[4]; } u0, u1;
#pragma unroll
    for (int jj = 0; jj < 4; ++jj) {
      u0.h[jj] = __float22bfloat162_rn(make_float2(bv0[2 * jj], bv0[2 * jj + 1]));
      u1.h[jj] = __float22bfloat162_rn(make_float2(bv1[2 * jj], bv1[2 * jj + 1]));
    }
    f32x4 acc[4];
#pragma unroll
    for (int mt = 0; mt < 4; ++mt) {
      acc[mt] = (f32x4){0.f, 0.f, 0.f, 0.f};
      acc[mt] = __builtin_amdgcn_mfma_f32_16x16x32_bf16(A[mt][0], u0.v, acc[mt], 0, 0, 0);
      acc[mt] = __builtin_amdgcn_mfma_f32_16x16x32_bf16(A[mt][1], u1.v, acc[mt], 0, 0, 0);
    }
    // this lane holds rows {mt*16 + q*4 + r} of column (n0 + nt*16 + c)
    float sum = 0.f, mxv = -3.4e38f;
#pragma unroll
    for (int mt = 0; mt < 4; ++mt)
#pragma unroll
      for (int r = 0; r < 4; ++r) {
        float v = acc[mt][r];
        sum += v;
        mxv = fmaxf(mxv, v);
      }
    sum += __shfl_xor(sum, 16);
    sum += __shfl_xor(sum, 32);
    mxv = fmaxf(mxv, __shfl_xor(mxv, 16));
    mxv = fmaxf(mxv, __shfl_xor(mxv, 32));
    int px = n0 + d + c;
    if (q == 0) poolp[px] = sum * (1.f / 64.f);
    if (q == 1) poolp[HW + px] = mxv;
  }
}

// ---------------- kernel 4: conv1 (2->1 ch, 3x3 SAME) + relu ----------------
__global__ __launch_bounds__(256) void k_conv1(const float* __restrict__ pool,
                                               float* __restrict__ t1,
                                               const float* __restrict__ cw,
                                               const float* __restrict__ cb) {
  int idx = blockIdx.x * 256 + threadIdx.x;   // 524288
  int t = idx >> 18;
  int rb = (idx >> 16) & 3;
  int n = idx & 65535;
  int h = n >> 8, w = n & 255;
  const float* pin = pool + ((size_t)((t << 2) | rb) << 17);
  float s = cb[0];
#pragma unroll
  for (int ci = 0; ci < 2; ++ci)
#pragma unroll
    for (int kh = -1; kh <= 1; ++kh)
#pragma unroll
      for (int kw = -1; kw <= 1; ++kw) {
        int hh = h + kh, ww = w + kw;
        if (hh >= 0 && hh < 256 && ww >= 0 && ww < 256)
          s += pin[ci * HW + (hh << 8) + ww] * cw[ci * 9 + (kh + 1) * 3 + (kw + 1)];
      }
  t1[((size_t)((t << 2) | rb) << 16) + n] = fmaxf(s, 0.f);
}

// ---------------- kernel 5: conv2 + fused per-block online softmax stats ----------------
__global__ __launch_bounds__(256) void k_conv2(const float* __restrict__ t1,
                                               float* __restrict__ y,
                                               const float* __restrict__ cw,
                                               const float* __restrict__ cb,
                                               float* __restrict__ bm,
                                               float* __restrict__ bs) {
  int bx = blockIdx.x;                        // 2048
  int tid = threadIdx.x;
  int idx = bx * 256 + tid;
  int t = idx >> 18;
  int rb = (idx >> 16) & 3;
  int n = idx & 65535;
  int h = n >> 8, w = n & 255;
  const float* pin = t1 + ((size_t)((t << 2) | rb) << 16);
  float s = cb[0];
#pragma unroll
  for (int kh = -1; kh <= 1; ++kh)
#pragma unroll
    for (int kw = -1; kw <= 1; ++kw) {
      int hh = h + kh, ww = w + kw;
      if (hh >= 0 && hh < 256 && ww >= 0 && ww < 256)
        s += pin[(hh << 8) + ww] * cw[(kh + 1) * 3 + (kw + 1)];
    }
  y[((size_t)((t << 2) | rb) << 16) + n] = s;

  // block max + sum(exp(y - max))
  __shared__ float red[4];
  __shared__ float Mbs;
  float m = s;
  for (int o = 32; o > 0; o >>= 1) m = fmaxf(m, __shfl_xor(m, o));
  if ((tid & 63) == 0) red[tid >> 6] = m;
  __syncthreads();
  if (tid == 0) Mbs = fmaxf(fmaxf(red[0], red[1]), fmaxf(red[2], red[3]));
  __syncthreads();
  float Mb = Mbs;
  float z = __expf(s - Mb);
  for (int o = 32; o > 0; o >>= 1) z += __shfl_xor(z, o);
  if ((tid & 63) == 0) red[tid >> 6] = z;
  __syncthreads();
  if (tid == 0) {
    bm[bx] = Mb;
    bs[bx] = (red[0] + red[1]) + (red[2] + red[3]);
  }
}

// ---------------- kernel 6: combine per-block stats -> M, 1/Z per slice ----------------
__global__ __launch_bounds__(256) void k_comb(const float* __restrict__ bm,
                                              const float* __restrict__ bs,
                                              float* __restrict__ mx,
                                              float* __restrict__ iz) {
  int s = blockIdx.x;       // 0..7
  int tid = threadIdx.x;    // 256 blocks per slice
  float m = bm[s * 256 + tid];
  float S = bs[s * 256 + tid];
  __shared__ float red[4];
  __shared__ float Msh;
  float mm = m;
  for (int o = 32; o > 0; o >>= 1) mm = fmaxf(mm, __shfl_xor(mm, o));
  if ((tid & 63) == 0) red[tid >> 6] = mm;
  __syncthreads();
  if (tid == 0) Msh = fmaxf(fmaxf(red[0], red[1]), fmaxf(red[2], red[3]));
  __syncthreads();
  float M = Msh;
  float z = __expf(m - M) * S;
  for (int o = 32; o > 0; o >>= 1) z += __shfl_xor(z, o);
  if ((tid & 63) == 0) red[tid >> 6] = z;
  __syncthreads();
  if (tid == 0) {
    mx[s] = M;
    iz[s] = 1.f / ((red[0] + red[1]) + (red[2] + red[3]));
  }
}

// ---------------- kernel 7: o = f * (1 + g) ----------------
__global__ __launch_bounds__(256) void k_final(const float* __restrict__ f1,
                                               const float* __restrict__ f2,
                                               const float* __restrict__ y,
                                               const float* __restrict__ mx,
                                               const float* __restrict__ iz,
                                               float* __restrict__ out) {
  size_t idx = (size_t)blockIdx.x * 256 + threadIdx.x;  // float4 index
  size_t e = idx << 2;
  int t = (int)(e >> 24);
  int r = (int)(e & 16777215);
  int b = r >> 22;
  int n = r & 65535;
  int s = (t << 2) | b;
  float M = mx[s], Z = iz[s];
  float4 yv = *(const float4*)(y + ((size_t)s << 16) + n);
  float4 fv = *(const float4*)((t ? f2 : f1) + r);
  float4 o;
  o.x = fv.x * (1.f + __expf(yv.x - M) * Z);
  o.y = fv.y * (1.f + __expf(yv.y - M) * Z);
  o.z = fv.z * (1.f + __expf(yv.z - M) * Z);
  o.w = fv.w * (1.f + __expf(yv.w - M) * Z);
  *(float4*)(out + e) = o;
}

extern "C" void kernel_launch(void* const* d_in, const int* in_sizes, int n_in,
                              void* d_out, int out_size, void* d_ws, size_t ws_size,
                              hipStream_t stream) {
  const float* f1 = (const float*)d_in[0];
  const float* f2 = (const float*)d_in[1];
  const float* w_avg1  = (const float*)d_in[2];
  const float* b_avg1  = (const float*)d_in[3];
  const float* w_max1  = (const float*)d_in[4];
  const float* b_max1  = (const float*)d_in[5];
  const float* w_avg11 = (const float*)d_in[6];
  const float* b_avg11 = (const float*)d_in[7];
  const float* w_max11 = (const float*)d_in[8];
  const float* b_max11 = (const float*)d_in[9];
  const float* w_avg2  = (const float*)d_in[10];
  const float* b_avg2  = (const float*)d_in[11];
  const float* w_max2  = (const float*)d_in[12];
  const float* b_max2  = (const float*)d_in[13];
  const float* w_avg22 = (const float*)d_in[14];
  const float* b_avg22 = (const float*)d_in[15];
  const float* w_max22 = (const float*)d_in[16];
  const float* b_max22 = (const float*)d_in[17];
  const float* conv1_w = (const float*)d_in[18];
  const float* conv1_b = (const float*)d_in[19];
  const float* conv2_w = (const float*)d_in[20];
  const float* conv2_b = (const float*)d_in[21];
  float* ws = (float*)d_ws;
  float* out = (float*)d_out;
  __hip_bfloat16* Pb = (__hip_bfloat16*)(ws + OFF_PB);

  k_reduce<<<512, 512, 0, stream>>>(f1, f2, ws);
  k_mlp<<<4, 64, 0, stream>>>(ws, Pb,
                              w_avg1, b_avg1, w_max1, b_max1,
                              w_avg11, b_avg11, w_max11, b_max11,
                              w_avg2, b_avg2, w_max2, b_max2,
                              w_avg22, b_avg22, w_max22, b_max22);
  k_pool<<<2048, 256, 0, stream>>>(f1, f2, Pb, ws + OFF_POOL);
  k_conv1<<<2048, 256, 0, stream>>>(ws + OFF_POOL, ws + OFF_T1, conv1_w, conv1_b);
  k_conv2<<<2048, 256, 0, stream>>>(ws + OFF_T1, ws + OFF_Y, conv2_w, conv2_b,
                                    ws + OFF_BM, ws + OFF_BS);
  k_comb<<<8, 256, 0, stream>>>(ws + OFF_BM, ws + OFF_BS, ws + OFF_MX, ws + OFF_IZ);
  k_final<<<32768, 256, 0, stream>>>(f1, f2, ws + OFF_Y, ws + OFF_MX, ws + OFF_IZ, out);
}